// Round 12
// baseline (146.709 us; speedup 1.0000x reference)
//
#include <hip/hip_runtime.h>
#include <hip/hip_bf16.h>

// SimpleDIN v12 — v11 + wide prep (257 blocks) + software-pipelined main
// loop (seq ids preloaded; next tile's table reads prefetched during the
// current tile's MFMA; pool from f32 directly).

typedef __attribute__((ext_vector_type(8))) short          bf16x8;
typedef __attribute__((ext_vector_type(8))) unsigned short u16x8;
typedef __attribute__((ext_vector_type(4))) float          f32x4;

__device__ __forceinline__ int swz_gran(int row, int g) {
    return row * 64 + ((g ^ (row & 7)) << 3);      // u16 index of 16B granule
}
__device__ __forceinline__ int swz_elem(int row, int col) {
    return row * 64 + (((col >> 3) ^ (row & 7)) << 3) + (col & 7);
}

// ---------------- Kernel P: prep (grid 257, 16 b per block) ----------------
extern "C" __global__ __launch_bounds__(256)
void din_prep(const int* __restrict__ item_ids,
              const float* __restrict__ item_table,
              const float* __restrict__ att_w1,
              const float* __restrict__ att_b1,
              __hip_bfloat16* __restrict__ gcb,   // [10240] Gb|Cb swizzled
              float* __restrict__ bias_out)       // [4096*80]
{
    const int t = threadIdx.x;
    if (blockIdx.x == 256) {                      // pack block
        for (int i = t; i < 64 * 80; i += 256) {
            const int d = i / 80;
            const int j = i - d * 80;
            const float g = att_w1[d * 80 + j] + att_w1[(192 + d) * 80 + j];
            const float c = att_w1[(128 + d) * 80 + j];
            gcb[swz_elem(j, d)]        = __float2bfloat16(g);
            gcb[5120 + swz_elem(j, d)] = __float2bfloat16(c);
        }
        return;
    }
    __shared__ float wdiff[64 * 80];              // 20 KB
    __shared__ float tgts[16 * 64];               // 4 KB
    const int b0 = blockIdx.x * 16;
    for (int i = t; i < 64 * 80; i += 256) {
        const int d = i / 80;
        const int j = i - d * 80;
        wdiff[i] = att_w1[(64 + d) * 80 + j] - att_w1[(192 + d) * 80 + j];
    }
    for (int i = t; i < 16 * 64; i += 256) {
        const int bl = i >> 6, d = i & 63;
        tgts[i] = item_table[(size_t)item_ids[b0 + bl] * 64 + d];
    }
    __syncthreads();
    for (int i = t; i < 16 * 80; i += 256) {
        const int bl = i / 80;
        const int j  = i - bl * 80;
        float acc = att_b1[j];
        #pragma unroll 8
        for (int d = 0; d < 64; ++d)
            acc = fmaf(tgts[bl * 64 + d], wdiff[d * 80 + j], acc);
        bias_out[(size_t)(b0 + bl) * 80 + j] = acc;
    }
}

// ---------------- Kernel M: main (grid 1024, 4 b per block) ----------------
struct __align__(16) LdsW {
    unsigned short gcb[10240];    // 20480 B: Gb [0,5120) | Cb [5120,10240)
    float w2[80];
    float biasw[4][80];
    float wsc[4][208];            // per-wave logit exchange
    float aux[4][128];
    float h1s[4][64];
};                                 // 28480 B

extern "C" __global__ __launch_bounds__(256, 4)
void din_main(const int* __restrict__ user_ids,
              const int* __restrict__ item_ids,
              const int* __restrict__ seq,
              const float* __restrict__ user_table,
              const float* __restrict__ item_table,
              const float* __restrict__ att_w2,
              const float* __restrict__ pred_w1,
              const float* __restrict__ pred_b1,
              const float* __restrict__ pred_w2,
              const float* __restrict__ pred_b2,
              const float* __restrict__ pred_w3,
              const float* __restrict__ pred_b3,
              const unsigned short* __restrict__ gcb_g,
              const float* __restrict__ bias_g,
              float* __restrict__ out)
{
    __shared__ LdsW L;
    const int t  = threadIdx.x;
    const int wv = t >> 6;                  // wave = one batch element
    const int l  = t & 63;
    const int lr = l & 15;
    const int ks = l >> 4;
    const int b  = blockIdx.x * 4 + wv;

    // stage shared constants (only barrier-protected data)
    {
        const u16x8* src = reinterpret_cast<const u16x8*>(gcb_g);
        u16x8* dst = reinterpret_cast<u16x8*>(L.gcb);
        #pragma unroll
        for (int i = 0; i < 5; ++i) dst[t + i * 256] = src[t + i * 256];
    }
    if (t < 80) L.w2[t] = att_w2[t];
    L.biasw[wv][l] = bias_g[(size_t)b * 80 + l];
    if (l < 16) L.biasw[wv][64 + l] = bias_g[(size_t)b * 80 + 64 + l];

    // per-lane tgt slices for A2/A3 = beh ⊙ tgt
    const int iid = item_ids[b];
    const float4* tp = reinterpret_cast<const float4*>(
        item_table + (size_t)iid * 64);
    const float4 tg0 = tp[2 * ks], tg1 = tp[2 * ks + 1];
    const float4 tg2 = tp[8 + 2 * ks], tg3 = tp[8 + 2 * ks + 1];
    const int uid = user_ids[b];
    const float uem = user_table[(size_t)uid * 64 + l];
    const int* seqb = seq + b * 200;

    // preload all 13 row ids (latency overlaps staging + barrier)
    int rows[13];
    #pragma unroll
    for (int mt = 0; mt < 13; ++mt) {
        const int srow = mt * 16 + lr;
        rows[mt] = (srow < 200) ? seqb[srow] : -1;
    }
    // prefetch tile 0's table reads
    float4 q0, q1, q2, q3;
    {
        const int r0 = rows[0] < 0 ? 0 : rows[0];
        const float4* rp = reinterpret_cast<const float4*>(
            item_table + (size_t)r0 * 64);
        q0 = rp[2 * ks]; q1 = rp[2 * ks + 1];
        q2 = rp[8 + 2 * ks]; q3 = rp[8 + 2 * ks + 1];
    }

    __syncthreads();                        // gcb/w2/bias ready

    // hoist epilogue constants
    float bias_r[5], w2_r[5];
    #pragma unroll
    for (int nt = 0; nt < 5; ++nt) {
        bias_r[nt] = L.biasw[wv][nt * 16 + lr];
        w2_r[nt]   = L.w2[nt * 16 + lr];
    }

    // ---- fused pipelined loop: 13 M-tiles ----
    float pl[8], ph[8];
    #pragma unroll
    for (int e = 0; e < 8; ++e) { pl[e] = 0.f; ph[e] = 0.f; }
    float mrun = -1e30f, ssum = 0.f;

    #pragma unroll
    for (int mt = 0; mt < 13; ++mt) {
        // prefetch next tile while this one computes
        float4 n0, n1, n2, n3;
        if (mt < 12) {
            const int rn = rows[mt + 1] < 0 ? 0 : rows[mt + 1];
            const float4* rp = reinterpret_cast<const float4*>(
                item_table + (size_t)rn * 64);
            n0 = rp[2 * ks]; n1 = rp[2 * ks + 1];
            n2 = rp[8 + 2 * ks]; n3 = rp[8 + 2 * ks + 1];
        }

        union { u16x8 u; bf16x8 bf; __hip_bfloat162 h2[4]; } A0, A1, A2, A3;
        A0.h2[0] = __float22bfloat162_rn(float2{q0.x, q0.y});
        A0.h2[1] = __float22bfloat162_rn(float2{q0.z, q0.w});
        A0.h2[2] = __float22bfloat162_rn(float2{q1.x, q1.y});
        A0.h2[3] = __float22bfloat162_rn(float2{q1.z, q1.w});
        A1.h2[0] = __float22bfloat162_rn(float2{q2.x, q2.y});
        A1.h2[1] = __float22bfloat162_rn(float2{q2.z, q2.w});
        A1.h2[2] = __float22bfloat162_rn(float2{q3.x, q3.y});
        A1.h2[3] = __float22bfloat162_rn(float2{q3.z, q3.w});
        A2.h2[0] = __float22bfloat162_rn(float2{q0.x * tg0.x, q0.y * tg0.y});
        A2.h2[1] = __float22bfloat162_rn(float2{q0.z * tg0.z, q0.w * tg0.w});
        A2.h2[2] = __float22bfloat162_rn(float2{q1.x * tg1.x, q1.y * tg1.y});
        A2.h2[3] = __float22bfloat162_rn(float2{q1.z * tg1.z, q1.w * tg1.w});
        A3.h2[0] = __float22bfloat162_rn(float2{q2.x * tg2.x, q2.y * tg2.y});
        A3.h2[1] = __float22bfloat162_rn(float2{q2.z * tg2.z, q2.w * tg2.w});
        A3.h2[2] = __float22bfloat162_rn(float2{q3.x * tg3.x, q3.y * tg3.y});
        A3.h2[3] = __float22bfloat162_rn(float2{q3.z * tg3.z, q3.w * tg3.w});

        f32x4 acc[5];
        #pragma unroll
        for (int nt = 0; nt < 5; ++nt)
            acc[nt] = (f32x4){0.f, 0.f, 0.f, 0.f};
        #pragma unroll
        for (int nt = 0; nt < 5; ++nt) {
            const int j = nt * 16 + lr;
            const bf16x8 g0 = *reinterpret_cast<const bf16x8*>(
                &L.gcb[swz_gran(j, ks)]);
            const bf16x8 g1 = *reinterpret_cast<const bf16x8*>(
                &L.gcb[swz_gran(j, 4 + ks)]);
            const bf16x8 c0 = *reinterpret_cast<const bf16x8*>(
                &L.gcb[5120 + swz_gran(j, ks)]);
            const bf16x8 c1 = *reinterpret_cast<const bf16x8*>(
                &L.gcb[5120 + swz_gran(j, 4 + ks)]);
            acc[nt] = __builtin_amdgcn_mfma_f32_16x16x32_bf16(A0.bf, g0, acc[nt], 0, 0, 0);
            acc[nt] = __builtin_amdgcn_mfma_f32_16x16x32_bf16(A1.bf, g1, acc[nt], 0, 0, 0);
            acc[nt] = __builtin_amdgcn_mfma_f32_16x16x32_bf16(A2.bf, c0, acc[nt], 0, 0, 0);
            acc[nt] = __builtin_amdgcn_mfma_f32_16x16x32_bf16(A3.bf, c1, acc[nt], 0, 0, 0);
        }

        // logits; invalid rows -> -1e30
        float pv[4];
        #pragma unroll
        for (int r = 0; r < 4; ++r) {
            const int s = mt * 16 + ks * 4 + r;
            float p = 0.f;
            #pragma unroll
            for (int nt = 0; nt < 5; ++nt)
                p += fmaxf(acc[nt][r] + bias_r[nt], 0.f) * w2_r[nt];
            p += __shfl_xor(p, 1);
            p += __shfl_xor(p, 2);
            p += __shfl_xor(p, 4);
            p += __shfl_xor(p, 8);
            if (s >= 200) p = -1e30f;
            pv[r] = p;
            if (lr == 0 && s < 200) L.wsc[wv][s] = p;
        }
        float tmax = fmaxf(fmaxf(pv[0], pv[1]), fmaxf(pv[2], pv[3]));
        tmax = fmaxf(tmax, __shfl_xor(tmax, 16));
        tmax = fmaxf(tmax, __shfl_xor(tmax, 32));
        if (tmax > mrun) {
            const float sc = __expf(mrun - tmax);
            #pragma unroll
            for (int e = 0; e < 8; ++e) { pl[e] *= sc; ph[e] *= sc; }
            ssum *= sc;
            mrun = tmax;
        }
        float w = 0.f;
        if (rows[mt] >= 0) w = __expf(L.wsc[wv][mt * 16 + lr] - mrun);
        ssum += w;
        // pool from f32 q directly (d = 8ks+e / 32+8ks+e)
        pl[0] = fmaf(w, q0.x, pl[0]); pl[1] = fmaf(w, q0.y, pl[1]);
        pl[2] = fmaf(w, q0.z, pl[2]); pl[3] = fmaf(w, q0.w, pl[3]);
        pl[4] = fmaf(w, q1.x, pl[4]); pl[5] = fmaf(w, q1.y, pl[5]);
        pl[6] = fmaf(w, q1.z, pl[6]); pl[7] = fmaf(w, q1.w, pl[7]);
        ph[0] = fmaf(w, q2.x, ph[0]); ph[1] = fmaf(w, q2.y, ph[1]);
        ph[2] = fmaf(w, q2.z, ph[2]); ph[3] = fmaf(w, q2.w, ph[3]);
        ph[4] = fmaf(w, q3.x, ph[4]); ph[5] = fmaf(w, q3.y, ph[5]);
        ph[6] = fmaf(w, q3.z, ph[6]); ph[7] = fmaf(w, q3.w, ph[7]);

        q0 = n0; q1 = n1; q2 = n2; q3 = n3;
    }

    // ---- reduce over lr (16 lanes) ----
    #pragma unroll
    for (int msk = 1; msk < 16; msk <<= 1) {
        #pragma unroll
        for (int e = 0; e < 8; ++e) {
            pl[e] += __shfl_xor(pl[e], msk);
            ph[e] += __shfl_xor(ph[e], msk);
        }
        ssum += __shfl_xor(ssum, msk);
    }
    const float inv = 1.f / ssum;
    if (lr == 0) {
        #pragma unroll
        for (int e = 0; e < 8; ++e) {
            L.aux[wv][64 + 8 * ks + e]      = pl[e] * inv;
            L.aux[wv][64 + 32 + 8 * ks + e] = ph[e] * inv;
        }
    }
    L.aux[wv][l] = uem;

    // ---- per-wave MLP 128 -> 64 -> 32 -> 1 ----
    float a0 = pred_b1[l], a1 = 0.f, a2 = 0.f, a3 = 0.f;
    #pragma unroll 4
    for (int k = 0; k < 128; k += 4) {
        a0 = fmaf(L.aux[wv][k],     pred_w1[k * 64 + l],       a0);
        a1 = fmaf(L.aux[wv][k + 1], pred_w1[(k + 1) * 64 + l], a1);
        a2 = fmaf(L.aux[wv][k + 2], pred_w1[(k + 2) * 64 + l], a2);
        a3 = fmaf(L.aux[wv][k + 3], pred_w1[(k + 3) * 64 + l], a3);
    }
    L.h1s[wv][l] = fmaxf((a0 + a1) + (a2 + a3), 0.f);
    const int j2 = l & 31;
    float c0 = pred_b2[j2], c1 = 0.f;
    #pragma unroll 4
    for (int k = 0; k < 64; k += 2) {
        c0 = fmaf(L.h1s[wv][k],     pred_w2[k * 32 + j2],       c0);
        c1 = fmaf(L.h1s[wv][k + 1], pred_w2[(k + 1) * 32 + j2], c1);
    }
    float p = fmaxf(c0 + c1, 0.f) * pred_w3[j2];
    p += __shfl_xor(p, 1);
    p += __shfl_xor(p, 2);
    p += __shfl_xor(p, 4);
    p += __shfl_xor(p, 8);
    p += __shfl_xor(p, 16);
    if (l == 0) {
        const float z = p + pred_b3[0];
        out[b] = 1.f / (1.f + __expf(-z));
    }
}

extern "C" void kernel_launch(void* const* d_in, const int* in_sizes, int n_in,
                              void* d_out, int out_size, void* d_ws, size_t ws_size,
                              hipStream_t stream)
{
    const int*   user_ids   = (const int*)  d_in[0];
    const int*   item_ids   = (const int*)  d_in[1];
    const int*   seq        = (const int*)  d_in[2];
    const float* user_table = (const float*)d_in[3];
    const float* item_table = (const float*)d_in[4];
    const float* att_w1     = (const float*)d_in[5];
    const float* att_b1     = (const float*)d_in[6];
    const float* att_w2     = (const float*)d_in[7];
    // d_in[8] = att_b2: cancels in softmax, unused
    const float* pred_w1    = (const float*)d_in[9];
    const float* pred_b1    = (const float*)d_in[10];
    const float* pred_w2    = (const float*)d_in[11];
    const float* pred_b2    = (const float*)d_in[12];
    const float* pred_w3    = (const float*)d_in[13];
    const float* pred_b3    = (const float*)d_in[14];
    float* out = (float*)d_out;

    __hip_bfloat16* gcb = (__hip_bfloat16*)d_ws;               // 20480 B
    float* bias_ws = (float*)((char*)d_ws + 20480);            // 4096*80 f32

    din_prep<<<257, 256, 0, stream>>>(item_ids, item_table, att_w1, att_b1,
                                      gcb, bias_ws);
    din_main<<<1024, 256, 0, stream>>>(user_ids, item_ids, seq,
                                       user_table, item_table, att_w2,
                                       pred_w1, pred_b1, pred_w2, pred_b2,
                                       pred_w3, pred_b3,
                                       (const unsigned short*)gcb, bias_ws,
                                       out);
}

// Round 13
// 63.219 us; speedup vs baseline: 2.3207x; 2.3207x over previous
//
#include <hip/hip_runtime.h>
#include <hip/hip_bf16.h>

// SimpleDIN v13 — v11 main loop (known-good, 60 VGPR, no spill) with the
// per-b bias GEMV replaced by one broadcast-A MFMA set inside main.
// Prep is now a pure pack: G=W1a+W1d | C=W1c | WD=W1b-W1d, bf16 swizzled.

typedef __attribute__((ext_vector_type(8))) short          bf16x8;
typedef __attribute__((ext_vector_type(8))) unsigned short u16x8;
typedef __attribute__((ext_vector_type(4))) float          f32x4;

__device__ __forceinline__ int swz_gran(int row, int g) {
    return row * 64 + ((g ^ (row & 7)) << 3);      // u16 index of 16B granule
}
__device__ __forceinline__ int swz_elem(int row, int col) {
    return row * 64 + (((col >> 3) ^ (row & 7)) << 3) + (col & 7);
}

// ---------------- Kernel P: pack only (grid 40) ----------------
extern "C" __global__ __launch_bounds__(256)
void din_prep(const float* __restrict__ att_w1,
              __hip_bfloat16* __restrict__ gcb)   // [15360] G|C|WD swizzled
{
    const int i = blockIdx.x * 256 + threadIdx.x;
    if (i < 64 * 80) {
        const int d = i / 80;
        const int j = i - d * 80;
        const float wa = att_w1[d * 80 + j];
        const float wb = att_w1[(64 + d) * 80 + j];
        const float wc = att_w1[(128 + d) * 80 + j];
        const float wd = att_w1[(192 + d) * 80 + j];
        const int sw = swz_elem(j, d);
        gcb[sw]         = __float2bfloat16(wa + wd);   // G
        gcb[5120 + sw]  = __float2bfloat16(wc);        // C
        gcb[10240 + sw] = __float2bfloat16(wb - wd);   // WD
    }
}

// ---------------- Kernel M: main (grid 1024, 4 b per block) ----------------
struct __align__(16) LdsW {
    unsigned short gcb[15360];    // 30720 B: G | C | WD (each 5120 u16)
    float w2[80];                 // 320
    float wsc[4][208];            // 3328 per-wave logit exchange
    float aux[4][128];            // 2048
    float h1s[4][64];             // 1024
};                                 // 37440 B -> 4 blocks/CU

extern "C" __global__ __launch_bounds__(256, 4)
void din_main(const int* __restrict__ user_ids,
              const int* __restrict__ item_ids,
              const int* __restrict__ seq,
              const float* __restrict__ user_table,
              const float* __restrict__ item_table,
              const float* __restrict__ att_b1,
              const float* __restrict__ att_w2,
              const float* __restrict__ pred_w1,
              const float* __restrict__ pred_b1,
              const float* __restrict__ pred_w2,
              const float* __restrict__ pred_b2,
              const float* __restrict__ pred_w3,
              const float* __restrict__ pred_b3,
              const unsigned short* __restrict__ gcb_g,
              float* __restrict__ out)
{
    __shared__ LdsW L;
    const int t  = threadIdx.x;
    const int wv = t >> 6;                  // wave = one batch element
    const int l  = t & 63;
    const int lr = l & 15;
    const int ks = l >> 4;
    const int b  = blockIdx.x * 4 + wv;

    // stage shared constants (only barrier-protected data)
    {
        const u16x8* src = reinterpret_cast<const u16x8*>(gcb_g);
        u16x8* dst = reinterpret_cast<u16x8*>(L.gcb);
        for (int i = t; i < 1920; i += 256) dst[i] = src[i];
    }
    if (t < 80) L.w2[t] = att_w2[t];

    // per-lane tgt slices (k = 8ks..8ks+7 and 32+8ks..32+8ks+7)
    const int iid = item_ids[b];
    const float4* tp = reinterpret_cast<const float4*>(
        item_table + (size_t)iid * 64);
    const float4 tg0 = tp[2 * ks], tg1 = tp[2 * ks + 1];
    const float4 tg2 = tp[8 + 2 * ks], tg3 = tp[8 + 2 * ks + 1];
    const int uid = user_ids[b];
    const float uem = user_table[(size_t)uid * 64 + l];
    const int* seqb = seq + b * 200;

    __syncthreads();                        // gcb/w2 ready

    // ---- bias_eff via broadcast-A MFMA: bias[j] = b1[j] + tgt·WD[:,j] ----
    float bias_r[5], w2_r[5];
    {
        union { u16x8 u; bf16x8 bf; __hip_bfloat162 h2[4]; } T0, T1;
        T0.h2[0] = __float22bfloat162_rn(float2{tg0.x, tg0.y});
        T0.h2[1] = __float22bfloat162_rn(float2{tg0.z, tg0.w});
        T0.h2[2] = __float22bfloat162_rn(float2{tg1.x, tg1.y});
        T0.h2[3] = __float22bfloat162_rn(float2{tg1.z, tg1.w});
        T1.h2[0] = __float22bfloat162_rn(float2{tg2.x, tg2.y});
        T1.h2[1] = __float22bfloat162_rn(float2{tg2.z, tg2.w});
        T1.h2[2] = __float22bfloat162_rn(float2{tg3.x, tg3.y});
        T1.h2[3] = __float22bfloat162_rn(float2{tg3.z, tg3.w});
        #pragma unroll
        for (int nt = 0; nt < 5; ++nt) {
            const int j = nt * 16 + lr;
            const bf16x8 wd0 = *reinterpret_cast<const bf16x8*>(
                &L.gcb[10240 + swz_gran(j, ks)]);
            const bf16x8 wd1 = *reinterpret_cast<const bf16x8*>(
                &L.gcb[10240 + swz_gran(j, 4 + ks)]);
            f32x4 bacc = (f32x4){0.f, 0.f, 0.f, 0.f};
            bacc = __builtin_amdgcn_mfma_f32_16x16x32_bf16(T0.bf, wd0, bacc, 0, 0, 0);
            bacc = __builtin_amdgcn_mfma_f32_16x16x32_bf16(T1.bf, wd1, bacc, 0, 0, 0);
            bias_r[nt] = bacc[0] + att_b1[j];   // all C rows equal
            w2_r[nt]   = L.w2[j];
        }
    }

    // ---- fused loop: 13 M-tiles, logits + online softmax-pooling ----
    float pl[8], ph[8];
    #pragma unroll
    for (int e = 0; e < 8; ++e) { pl[e] = 0.f; ph[e] = 0.f; }
    float mrun = -1e30f, ssum = 0.f;

    for (int mt = 0; mt < 13; ++mt) {
        const int srow = mt * 16 + lr;
        const bool val = srow < 200;
        const int row = val ? seqb[srow] : 0;
        const float4* rp = reinterpret_cast<const float4*>(
            item_table + (size_t)row * 64);
        float4 q0 = rp[2 * ks], q1 = rp[2 * ks + 1];
        float4 q2 = rp[8 + 2 * ks], q3 = rp[8 + 2 * ks + 1];
        if (!val) {
            q0 = make_float4(0.f, 0.f, 0.f, 0.f);
            q1 = make_float4(0.f, 0.f, 0.f, 0.f);
            q2 = make_float4(0.f, 0.f, 0.f, 0.f);
            q3 = make_float4(0.f, 0.f, 0.f, 0.f);
        }
        union { u16x8 u; bf16x8 bf; __hip_bfloat162 h2[4]; } A0, A1, A2, A3;
        A0.h2[0] = __float22bfloat162_rn(float2{q0.x, q0.y});
        A0.h2[1] = __float22bfloat162_rn(float2{q0.z, q0.w});
        A0.h2[2] = __float22bfloat162_rn(float2{q1.x, q1.y});
        A0.h2[3] = __float22bfloat162_rn(float2{q1.z, q1.w});
        A1.h2[0] = __float22bfloat162_rn(float2{q2.x, q2.y});
        A1.h2[1] = __float22bfloat162_rn(float2{q2.z, q2.w});
        A1.h2[2] = __float22bfloat162_rn(float2{q3.x, q3.y});
        A1.h2[3] = __float22bfloat162_rn(float2{q3.z, q3.w});
        A2.h2[0] = __float22bfloat162_rn(float2{q0.x * tg0.x, q0.y * tg0.y});
        A2.h2[1] = __float22bfloat162_rn(float2{q0.z * tg0.z, q0.w * tg0.w});
        A2.h2[2] = __float22bfloat162_rn(float2{q1.x * tg1.x, q1.y * tg1.y});
        A2.h2[3] = __float22bfloat162_rn(float2{q1.z * tg1.z, q1.w * tg1.w});
        A3.h2[0] = __float22bfloat162_rn(float2{q2.x * tg2.x, q2.y * tg2.y});
        A3.h2[1] = __float22bfloat162_rn(float2{q2.z * tg2.z, q2.w * tg2.w});
        A3.h2[2] = __float22bfloat162_rn(float2{q3.x * tg3.x, q3.y * tg3.y});
        A3.h2[3] = __float22bfloat162_rn(float2{q3.z * tg3.z, q3.w * tg3.w});

        f32x4 acc[5];
        #pragma unroll
        for (int nt = 0; nt < 5; ++nt)
            acc[nt] = (f32x4){0.f, 0.f, 0.f, 0.f};
        #pragma unroll
        for (int nt = 0; nt < 5; ++nt) {
            const int j = nt * 16 + lr;
            const bf16x8 g0 = *reinterpret_cast<const bf16x8*>(
                &L.gcb[swz_gran(j, ks)]);
            const bf16x8 g1 = *reinterpret_cast<const bf16x8*>(
                &L.gcb[swz_gran(j, 4 + ks)]);
            const bf16x8 c0 = *reinterpret_cast<const bf16x8*>(
                &L.gcb[5120 + swz_gran(j, ks)]);
            const bf16x8 c1 = *reinterpret_cast<const bf16x8*>(
                &L.gcb[5120 + swz_gran(j, 4 + ks)]);
            acc[nt] = __builtin_amdgcn_mfma_f32_16x16x32_bf16(A0.bf, g0, acc[nt], 0, 0, 0);
            acc[nt] = __builtin_amdgcn_mfma_f32_16x16x32_bf16(A1.bf, g1, acc[nt], 0, 0, 0);
            acc[nt] = __builtin_amdgcn_mfma_f32_16x16x32_bf16(A2.bf, c0, acc[nt], 0, 0, 0);
            acc[nt] = __builtin_amdgcn_mfma_f32_16x16x32_bf16(A3.bf, c1, acc[nt], 0, 0, 0);
        }

        // logits; invalid rows -> -1e30
        float pv[4];
        #pragma unroll
        for (int r = 0; r < 4; ++r) {
            const int s = mt * 16 + ks * 4 + r;
            float p = 0.f;
            #pragma unroll
            for (int nt = 0; nt < 5; ++nt)
                p += fmaxf(acc[nt][r] + bias_r[nt], 0.f) * w2_r[nt];
            p += __shfl_xor(p, 1);
            p += __shfl_xor(p, 2);
            p += __shfl_xor(p, 4);
            p += __shfl_xor(p, 8);
            if (s >= 200) p = -1e30f;
            pv[r] = p;
            if (lr == 0 && s < 200) L.wsc[wv][s] = p;
        }
        float tmax = fmaxf(fmaxf(pv[0], pv[1]), fmaxf(pv[2], pv[3]));
        tmax = fmaxf(tmax, __shfl_xor(tmax, 16));
        tmax = fmaxf(tmax, __shfl_xor(tmax, 32));
        if (tmax > mrun) {
            const float sc = __expf(mrun - tmax);
            #pragma unroll
            for (int e = 0; e < 8; ++e) { pl[e] *= sc; ph[e] *= sc; }
            ssum *= sc;
            mrun = tmax;
        }
        float w = 0.f;
        if (val) w = __expf(L.wsc[wv][srow] - mrun);
        ssum += w;
        pl[0] = fmaf(w, q0.x, pl[0]); pl[1] = fmaf(w, q0.y, pl[1]);
        pl[2] = fmaf(w, q0.z, pl[2]); pl[3] = fmaf(w, q0.w, pl[3]);
        pl[4] = fmaf(w, q1.x, pl[4]); pl[5] = fmaf(w, q1.y, pl[5]);
        pl[6] = fmaf(w, q1.z, pl[6]); pl[7] = fmaf(w, q1.w, pl[7]);
        ph[0] = fmaf(w, q2.x, ph[0]); ph[1] = fmaf(w, q2.y, ph[1]);
        ph[2] = fmaf(w, q2.z, ph[2]); ph[3] = fmaf(w, q2.w, ph[3]);
        ph[4] = fmaf(w, q3.x, ph[4]); ph[5] = fmaf(w, q3.y, ph[5]);
        ph[6] = fmaf(w, q3.z, ph[6]); ph[7] = fmaf(w, q3.w, ph[7]);
    }

    // ---- reduce over lr (16 lanes) ----
    #pragma unroll
    for (int msk = 1; msk < 16; msk <<= 1) {
        #pragma unroll
        for (int e = 0; e < 8; ++e) {
            pl[e] += __shfl_xor(pl[e], msk);
            ph[e] += __shfl_xor(ph[e], msk);
        }
        ssum += __shfl_xor(ssum, msk);
    }
    const float inv = 1.f / ssum;
    if (lr == 0) {
        #pragma unroll
        for (int e = 0; e < 8; ++e) {
            L.aux[wv][64 + 8 * ks + e]      = pl[e] * inv;
            L.aux[wv][64 + 32 + 8 * ks + e] = ph[e] * inv;
        }
    }
    L.aux[wv][l] = uem;

    // ---- per-wave MLP 128 -> 64 -> 32 -> 1 ----
    float a0 = pred_b1[l], a1 = 0.f, a2 = 0.f, a3 = 0.f;
    #pragma unroll 4
    for (int k = 0; k < 128; k += 4) {
        a0 = fmaf(L.aux[wv][k],     pred_w1[k * 64 + l],       a0);
        a1 = fmaf(L.aux[wv][k + 1], pred_w1[(k + 1) * 64 + l], a1);
        a2 = fmaf(L.aux[wv][k + 2], pred_w1[(k + 2) * 64 + l], a2);
        a3 = fmaf(L.aux[wv][k + 3], pred_w1[(k + 3) * 64 + l], a3);
    }
    L.h1s[wv][l] = fmaxf((a0 + a1) + (a2 + a3), 0.f);
    const int j2 = l & 31;
    float c0 = pred_b2[j2], c1 = 0.f;
    #pragma unroll 4
    for (int k = 0; k < 64; k += 2) {
        c0 = fmaf(L.h1s[wv][k],     pred_w2[k * 32 + j2],       c0);
        c1 = fmaf(L.h1s[wv][k + 1], pred_w2[(k + 1) * 32 + j2], c1);
    }
    float p = fmaxf(c0 + c1, 0.f) * pred_w3[j2];
    p += __shfl_xor(p, 1);
    p += __shfl_xor(p, 2);
    p += __shfl_xor(p, 4);
    p += __shfl_xor(p, 8);
    p += __shfl_xor(p, 16);
    if (l == 0) {
        const float z = p + pred_b3[0];
        out[b] = 1.f / (1.f + __expf(-z));
    }
}

extern "C" void kernel_launch(void* const* d_in, const int* in_sizes, int n_in,
                              void* d_out, int out_size, void* d_ws, size_t ws_size,
                              hipStream_t stream)
{
    const int*   user_ids   = (const int*)  d_in[0];
    const int*   item_ids   = (const int*)  d_in[1];
    const int*   seq        = (const int*)  d_in[2];
    const float* user_table = (const float*)d_in[3];
    const float* item_table = (const float*)d_in[4];
    const float* att_w1     = (const float*)d_in[5];
    const float* att_b1     = (const float*)d_in[6];
    const float* att_w2     = (const float*)d_in[7];
    // d_in[8] = att_b2: cancels in softmax, unused
    const float* pred_w1    = (const float*)d_in[9];
    const float* pred_b1    = (const float*)d_in[10];
    const float* pred_w2    = (const float*)d_in[11];
    const float* pred_b2    = (const float*)d_in[12];
    const float* pred_w3    = (const float*)d_in[13];
    const float* pred_b3    = (const float*)d_in[14];
    float* out = (float*)d_out;

    __hip_bfloat16* gcb = (__hip_bfloat16*)d_ws;               // 30720 B

    din_prep<<<40, 256, 0, stream>>>(att_w1, gcb);
    din_main<<<1024, 256, 0, stream>>>(user_ids, item_ids, seq,
                                       user_table, item_table,
                                       att_b1, att_w2,
                                       pred_w1, pred_b1, pred_w2, pred_b2,
                                       pred_w3, pred_b3,
                                       (const unsigned short*)gcb,
                                       out);
}